// Round 1
// baseline (926.472 us; speedup 1.0000x reference)
//
#include <hip/hip_runtime.h>
#include <stdint.h>

#define NROWS 131072
#define DIM 512
#define NCLS 100
#define LAMB 0.001f

// out layout (floats): mu[512] | temp[512*512] | Sw | Sb | St
#define OFF_T  512
#define OFF_SW 262656
#define OFF_SB 524800
#define OFF_ST 786944

typedef __attribute__((ext_vector_type(8))) short short8;
typedef __attribute__((ext_vector_type(8))) unsigned short ushort8;
typedef __attribute__((ext_vector_type(4))) float f32x4;

__device__ inline unsigned short f2bf(float f){
  unsigned int u = __float_as_uint(f);
  return (unsigned short)((u + 0x7FFFu + ((u>>16)&1u)) >> 16);
}

// ---------------- zero sums/counts ----------------
__global__ void k_zero(float* sums, int* counts){
  int g = blockIdx.x*256 + threadIdx.x;
  if (g < NCLS*DIM) sums[g] = 0.f;
  if (g < 128) counts[g] = 0;
}

// ---------------- per-class sums + counts ----------------
// grid (32 row-chunks, 8 col-groups of 64), 256 threads
__global__ __launch_bounds__(256) void k_stats(const float* __restrict__ X, const int* __restrict__ y,
                                               float* sums, int* counts){
  __shared__ float cls[NCLS][64];
  __shared__ int ccnt[NCLS];
  int tid = threadIdx.x;
  int chunk = blockIdx.x, cg = blockIdx.y;
  for (int i = tid; i < NCLS*64; i += 256) ((float*)cls)[i] = 0.f;
  if (cg == 0) for (int i = tid; i < NCLS; i += 256) ccnt[i] = 0;
  __syncthreads();
  int lane16 = tid & 15, rowoff = tid >> 4;
  int colbase = cg*64 + lane16*4;
  for (int p = 0; p < 256; ++p){
    int r = chunk*4096 + p*16 + rowoff;
    int c = y[r];
    float4 v = *(const float4*)&X[(size_t)r*DIM + colbase];
    atomicAdd(&cls[c][lane16*4+0], v.x);
    atomicAdd(&cls[c][lane16*4+1], v.y);
    atomicAdd(&cls[c][lane16*4+2], v.z);
    atomicAdd(&cls[c][lane16*4+3], v.w);
    if (cg == 0 && lane16 == 0) atomicAdd(&ccnt[c], 1);
  }
  __syncthreads();
  for (int i = tid; i < NCLS*64; i += 256){
    int c = i >> 6, col = i & 63;
    atomicAdd(&sums[c*DIM + cg*64 + col], cls[c][col]);
  }
  if (cg == 0) for (int i = tid; i < NCLS; i += 256) atomicAdd(&counts[i], ccnt[i]);
}

// ---------------- X (NxD f32) -> XT (DxN bf16) ----------------
// grid (2048, 8), 256 threads; 64x64 tiles via f32 LDS
__global__ __launch_bounds__(256) void k_transpose(const float* __restrict__ X, unsigned short* __restrict__ XT){
  __shared__ float t[64][68];
  int tid = threadIdx.x;
  int r0 = blockIdx.x*64, d0 = blockIdx.y*64;
  int lane16 = tid & 15, rq = tid >> 4;
  #pragma unroll
  for (int p = 0; p < 4; ++p){
    int r = p*16 + rq;
    float4 v = *(const float4*)&X[(size_t)(r0+r)*DIM + d0 + lane16*4];
    t[lane16*4+0][r] = v.x; t[lane16*4+1][r] = v.y;
    t[lane16*4+2][r] = v.z; t[lane16*4+3][r] = v.w;
  }
  __syncthreads();
  int d = tid >> 2, nb = (tid & 3)*16;
  ushort8 o0, o1;
  #pragma unroll
  for (int q = 0; q < 8; ++q){ o0[q] = f2bf(t[d][nb+q]); o1[q] = f2bf(t[d][nb+8+q]); }
  *(ushort8*)&XT[(size_t)(d0+d)*NROWS + r0 + nb]     = o0;
  *(ushort8*)&XT[(size_t)(d0+d)*NROWS + r0 + nb + 8] = o1;
}

// ---------------- G = XT * XT^T partials (triangle tiles) ----------------
// grid (64 k-chunks, 10 tiles), 256 threads (4 waves), 128x128 tile, BK=64
__global__ __launch_bounds__(256) void k_gemm(const unsigned short* __restrict__ XT, float* __restrict__ part){
  int kc = blockIdx.x, t = blockIdx.y;
  int i, j;
  if (t < 4){ i = 0; j = t; } else if (t < 7){ i = 1; j = t-3; }
  else if (t < 9){ i = 2; j = t-6; } else { i = 3; j = 3; }
  __shared__ unsigned short As[128*64];
  __shared__ unsigned short Bs[128*64];
  int tid = threadIdx.x, wave = tid >> 6, lane = tid & 63;
  int wr = (wave >> 1)*64, wc = (wave & 1)*64;
  f32x4 acc[4][4] = {};
  const unsigned short* Ab = XT + (size_t)i*128*NROWS + (size_t)kc*2048;
  const unsigned short* Bb = XT + (size_t)j*128*NROWS + (size_t)kc*2048;
  for (int ks = 0; ks < 32; ++ks){
    int k0 = ks*64;
    __syncthreads();
    #pragma unroll
    for (int rr = 0; rr < 4; ++rr){
      int ch = rr*256 + tid;
      int row = ch >> 3, ko = (ch & 7)*8;
      *(ushort8*)&As[row*64+ko] = *(const ushort8*)&Ab[(size_t)row*NROWS + k0 + ko];
      *(ushort8*)&Bs[row*64+ko] = *(const ushort8*)&Bb[(size_t)row*NROWS + k0 + ko];
    }
    __syncthreads();
    #pragma unroll
    for (int kk = 0; kk < 2; ++kk){
      short8 a[4], b[4];
      int ko = kk*32 + (lane >> 4)*8;
      #pragma unroll
      for (int m = 0; m < 4; ++m) a[m] = *(const short8*)&As[(wr + m*16 + (lane & 15))*64 + ko];
      #pragma unroll
      for (int n = 0; n < 4; ++n) b[n] = *(const short8*)&Bs[(wc + n*16 + (lane & 15))*64 + ko];
      #pragma unroll
      for (int m = 0; m < 4; ++m)
        #pragma unroll
        for (int n = 0; n < 4; ++n)
          acc[m][n] = __builtin_amdgcn_mfma_f32_16x16x32_bf16(a[m], b[n], acc[m][n], 0, 0, 0);
    }
  }
  float* P = part + ((size_t)t*64 + kc)*16384;
  #pragma unroll
  for (int m = 0; m < 4; ++m)
    #pragma unroll
    for (int n = 0; n < 4; ++n)
      #pragma unroll
      for (int q = 0; q < 4; ++q){
        int row = wr + m*16 + (lane >> 4)*4 + q;
        int col = wc + n*16 + (lane & 15);
        P[row*128 + col] = acc[m][n][q];
      }
}

// ---------------- reduce partials -> G (with symmetric mirror) ----------------
__global__ __launch_bounds__(256) void k_reduce(const float* __restrict__ part, float* __restrict__ G){
  int p = blockIdx.x, t = blockIdx.y;
  int i, j;
  if (t < 4){ i = 0; j = t; } else if (t < 7){ i = 1; j = t-3; }
  else if (t < 9){ i = 2; j = t-6; } else { i = 3; j = 3; }
  int e = p*256 + threadIdx.x;
  int r = e >> 7, c = e & 127;
  float s = 0.f;
  for (int kc = 0; kc < 64; ++kc) s += part[((size_t)t*64 + kc)*16384 + e];
  G[(i*128+r)*DIM + j*128+c] = s;
  G[(j*128+c)*DIM + i*128+r] = s;
}

// ---------------- mean, coefs, w-bar; writes mu ----------------
__global__ __launch_bounds__(512) void k_post(const float* __restrict__ sums, const int* __restrict__ counts,
                                              float* mean, float* coef1, float* coef2, float* scal,
                                              float* out){
  int tid = threadIdx.x;
  float s = 0.f;
  for (int c = 0; c < NCLS; ++c) s += sums[c*DIM + tid];
  float m = s/(float)NROWS;
  mean[tid] = m; out[tid] = m;
  if (tid < NCLS){
    float cc = (float)counts[tid];
    coef1[tid] = cc*cc/((cc-1.f)*(float)NROWS);  // w_c * count_c
    coef2[tid] = cc/(float)NROWS;
  }
  __syncthreads();
  if (tid == 0){
    float wb = 0.f;
    for (int c = 0; c < NCLS; ++c) wb += coef1[c];
    scal[0] = wb/(float)NROWS;                   // count-weighted mean of w_c
  }
}

// ---------------- assemble Sw, Sb, St, E=I-Sw_reg, T0=Sb ----------------
// grid (8,8), 256 threads, 4x4 micro-tile
__global__ __launch_bounds__(256) void k_assemble(const float* __restrict__ G, const float* __restrict__ sums,
                const int* __restrict__ counts, const float* __restrict__ mean,
                const float* __restrict__ coef1, const float* __restrict__ coef2, const float* __restrict__ scal,
                float* __restrict__ out, float* __restrict__ E, float* __restrict__ Tp){
  int I = blockIdx.y, J = blockIdx.x;
  int d0 = I*64, e0 = J*64;
  __shared__ float md[8][64], me[8][64];
  __shared__ float c1[8], c2[8];
  __shared__ float meanD[64], meanE[64];
  int tid = threadIdx.x;
  if (tid < 64) meanD[tid] = mean[d0+tid];
  else if (tid < 128) meanE[tid-64] = mean[e0+tid-64];
  float accC[4][4] = {}, accB[4][4] = {};
  int ty = tid >> 4, tx = tid & 15;
  for (int ch = 0; ch < 13; ++ch){
    __syncthreads();
    for (int id = tid; id < 512; id += 256){
      int cl = ch*8 + (id >> 6), col = id & 63;
      float mdv = 0.f, mev = 0.f;
      if (cl < NCLS){
        float cc = (float)counts[cl];
        mdv = sums[cl*DIM + d0 + col]/cc;
        mev = sums[cl*DIM + e0 + col]/cc;
      }
      md[id>>6][col] = mdv; me[id>>6][col] = mev;
    }
    if (tid < 8){
      int cl = ch*8 + tid;
      c1[tid] = (cl < NCLS) ? coef1[cl] : 0.f;
      c2[tid] = (cl < NCLS) ? coef2[cl] : 0.f;
    }
    __syncthreads();
    for (int cc = 0; cc < 8; ++cc){
      float w1 = c1[cc], w2 = c2[cc];
      float a[4], b[4], da[4], db[4];
      #pragma unroll
      for (int p = 0; p < 4; ++p){ a[p] = md[cc][ty*4+p]; da[p] = a[p] - meanD[ty*4+p]; }
      #pragma unroll
      for (int q = 0; q < 4; ++q){ b[q] = me[cc][tx*4+q]; db[q] = b[q] - meanE[tx*4+q]; }
      #pragma unroll
      for (int p = 0; p < 4; ++p)
        #pragma unroll
        for (int q = 0; q < 4; ++q){
          accC[p][q] += w1*a[p]*b[q];
          accB[p][q] += w2*da[p]*db[q];
        }
    }
  }
  float wbar = scal[0];
  #pragma unroll
  for (int p = 0; p < 4; ++p){
    int row = d0 + ty*4 + p;
    #pragma unroll
    for (int q = 0; q < 4; ++q){
      int col = e0 + tx*4 + q;
      float g  = G[row*DIM + col];
      float sw = wbar*g - accC[p][q];
      float st = (g - (float)NROWS*meanD[ty*4+p]*meanE[tx*4+q])/((float)NROWS - 1.f);
      float sb = accB[p][q];
      out[OFF_SW + row*DIM + col] = sw;
      out[OFF_SB + row*DIM + col] = sb;
      out[OFF_ST + row*DIM + col] = st;
      E[row*DIM + col]  = ((row == col) ? (1.f - LAMB) : 0.f) - sw;
      Tp[row*DIM + col] = sb;
    }
  }
}

// ---------------- Neumann step: Tout = Sb + E*Tin ----------------
__global__ __launch_bounds__(256) void k_neumann(const float* __restrict__ E, const float* __restrict__ Tin,
                                                 const float* __restrict__ Sb, float* __restrict__ Tout){
  int I = blockIdx.y, J = blockIdx.x;
  __shared__ float Es[64][68], Ts[64][68];
  int tid = threadIdx.x;
  int ty = tid >> 4, tx = tid & 15;
  float acc[4][4] = {};
  for (int kc = 0; kc < 8; ++kc){
    int k0 = kc*64;
    __syncthreads();
    for (int id = tid; id < 1024; id += 256){
      int row = id >> 4; int col = (id & 15)*4;
      *(float4*)&Es[row][col] = *(const float4*)&E[(I*64+row)*DIM + k0 + col];
      *(float4*)&Ts[row][col] = *(const float4*)&Tin[(k0+row)*DIM + J*64 + col];
    }
    __syncthreads();
    for (int k = 0; k < 64; ++k){
      float a[4], b[4];
      #pragma unroll
      for (int p = 0; p < 4; ++p) a[p] = Es[ty*4+p][k];
      #pragma unroll
      for (int q = 0; q < 4; ++q) b[q] = Ts[k][tx*4+q];
      #pragma unroll
      for (int p = 0; p < 4; ++p)
        #pragma unroll
        for (int q = 0; q < 4; ++q) acc[p][q] += a[p]*b[q];
    }
  }
  #pragma unroll
  for (int p = 0; p < 4; ++p){
    int row = I*64 + ty*4 + p;
    #pragma unroll
    for (int q = 0; q < 4; ++q){
      int col = J*64 + tx*4 + q;
      Tout[row*DIM + col] = Sb[row*DIM + col] + acc[p][q];
    }
  }
}

// ---------------- temp = (T + T^T)/2 ----------------
__global__ __launch_bounds__(256) void k_final(const float* __restrict__ T, float* __restrict__ out){
  int g = blockIdx.x*256 + threadIdx.x;
  int d = g >> 9, e = g & 511;
  out[OFF_T + g] = 0.5f*(T[g] + T[e*DIM + d]);
}

extern "C" void kernel_launch(void* const* d_in, const int* in_sizes, int n_in,
                              void* d_out, int out_size, void* d_ws, size_t ws_size,
                              hipStream_t stream){
  const float* X = (const float*)d_in[0];
  const int*   y = (const int*)d_in[1];
  float* out = (float*)d_out;
  char* ws = (char*)d_ws;

  unsigned short* XT = (unsigned short*)(ws + 0);              // 134217728 B
  float* part  = (float*)(ws + 134217728);                     // 41943040 B
  float* sums  = (float*)(ws + 176160768);                     // 204800 B
  int*   counts= (int*)  (ws + 176365568);                     // 1024 B
  float* mean  = (float*)(ws + 176366592);                     // 2048 B
  float* coef1 = (float*)(ws + 176368640);                     // 1024 B
  float* coef2 = (float*)(ws + 176369664);                     // 1024 B
  float* scal  = (float*)(ws + 176370688);                     // 1024 B
  float* G     = (float*)(ws + 176371712);                     // 1 MB
  float* E     = (float*)(ws + 177420288);                     // 1 MB
  float* Tp    = (float*)(ws + 178468864);                     // 1 MB
  float* Tq    = (float*)(ws + 179517440);                     // 1 MB

  k_zero<<<200, 256, 0, stream>>>(sums, counts);
  k_stats<<<dim3(32, 8), 256, 0, stream>>>(X, y, sums, counts);
  k_transpose<<<dim3(2048, 8), 256, 0, stream>>>(X, XT);
  k_gemm<<<dim3(64, 10), 256, 0, stream>>>(XT, part);
  k_reduce<<<dim3(64, 10), 256, 0, stream>>>(part, G);
  k_post<<<1, 512, 0, stream>>>(sums, counts, mean, coef1, coef2, scal, out);
  k_assemble<<<dim3(8, 8), 256, 0, stream>>>(G, sums, counts, mean, coef1, coef2, scal, out, E, Tp);
  const float* Sb = out + OFF_SB;
  k_neumann<<<dim3(8, 8), 256, 0, stream>>>(E, Tp, Sb, Tq);
  k_neumann<<<dim3(8, 8), 256, 0, stream>>>(E, Tq, Sb, Tp);
  k_neumann<<<dim3(8, 8), 256, 0, stream>>>(E, Tp, Sb, Tq);
  k_neumann<<<dim3(8, 8), 256, 0, stream>>>(E, Tq, Sb, Tp);
  k_final<<<1024, 256, 0, stream>>>(Tp, out);
}